// Round 13
// baseline (49.805 us; speedup 1.0000x reference)
//
#include <hip/hip_runtime.h>
#include <math.h>

// Fuzzy capsule routing, MI355X — round 12 (resubmit after infra failure):
// phase-3 lp reads moved to VMEM. route1 writes lpT[n][m][16] (own chunk);
// routes 2/3 stage lp from lpT (float4->b128) and phase 3 reads lp rows from
// GLOBAL (L1-broadcast), halving DS issues/wave. Everything else = R11.

#define NB 64
#define NK 20
#define NSPLIT 8
#define CPB 4
#define LPP 36            // lp pair-row stride: [mp][ m&1 ? 16..31 : 0..15 ]
#define RST 260           // r_s row stride
#define ROWF 28           // fused row: [0..15]=-2Wg, [16..25]=WW^T, [26]=|g|^2
#define PROW 18           // P row per k: [0..15]=u, [16]=s, [17]=rqv

__device__ __forceinline__ float frcp(float x){ return __builtin_amdgcn_rcpf(x); }
__device__ __forceinline__ float4 ldg4(const float* p){ return *(const float4*)p; }

// ---------------- final reduce: g3, sigma, a ----------------
__global__ __launch_bounds__(256)
void k_redfinal(const float* __restrict__ P, const float* __restrict__ beta,
                float* __restrict__ out)
{
    const int q = blockIdx.x, n = blockIdx.y, tid = threadIdx.x;
    __shared__ float tmp_s[5*PROW];
    if (tid < 5*PROW){
        float acc = 0.f;
        const float* p = P + (size_t)n*NSPLIT*NK*PROW + q*5*PROW + tid;
        #pragma unroll
        for (int s=0;s<NSPLIT;s++) acc += p[s*NK*PROW];
        tmp_s[tid] = acc;
    }
    __syncthreads();
    if (tid < 80){
        int kloc = tid>>4, d = tid&15;
        out[1280 + n*320 + q*80 + tid] = tmp_s[kloc*PROW + d] / tmp_s[kloc*PROW + 16];
    }
    if (tid < 5){
        const int k = q*5 + tid;
        float s   = tmp_s[tid*PROW + 16];
        float rqv = tmp_s[tid*PROW + 17];
        float usq = 0.f;
        #pragma unroll
        for (int d=0;d<16;d++){ float u = tmp_s[tid*PROW + d]; usq += u*u; }
        float is = 1.f/s;
        float sig = is*rqv - (is*is)*usq;     // (1/s)Sum r|V|^2 - |g3|^2
        float z = beta[k] - 0.5f*logf(sig);   // LAMBDA = 1
        out[n*NK + k] = 1.f/(1.f + expf(-z));
    }
}

// ---------------- routing iteration ----------------
// FIRST: stage from l, build lpT, phase3 from LDS.
// Else : stage from lpT (float4), phase3 lp from GLOBAL lpT.
// MODE1: also accumulate rqv (wave-reduced in phase 1).
template<int FIRST, int MODE>
__global__ __launch_bounds__(256, 2)
void k_route(const float* __restrict__ l, const float* __restrict__ wgt,
             const float* __restrict__ g_in, const float* __restrict__ Pprev,
             float* __restrict__ Pout, float* __restrict__ lpT)
{
    const int split = blockIdx.x, n = blockIdx.y, tid = threadIdx.x;
    const int c0 = split*CPB;

    __shared__ __align__(16) float lp_s[128*LPP];        // 4608
    __shared__ __align__(16) float r_s[NK*RST];          // 5200
    __shared__ __align__(16) float mw_s[CPB*NK*ROWF];    // 2240
    __shared__ __align__(16) float wt_s[CPB*NK*16];      // 1280
    __shared__ __align__(16) float red_s[4*NK*PROW];     // 1440 (tmp alias early)
    __shared__ __align__(16) float rqw_s[4*24];          // 96
    __shared__ __align__(16) float g_s[NK*16];           // 320

    float* lpTn = lpT + ((size_t)n*32 + c0)*1024;        // this block's chunk

    // ---- A: stage lp, W; g source ----
    if (FIRST){
        const float* lsrc = l + ((size_t)n*32 + c0)*1024;
        #pragma unroll
        for (int i=0;i<16;i++){
            int t = i*256 + tid;
            int cl = t>>10, dd = (t>>6)&15, wh = t&63;
            int m = cl*64 + wh;
            lp_s[(m>>1)*LPP + (m&1)*16 + dd] = lsrc[t];
        }
    } else {
        #pragma unroll
        for (int i=0;i<4;i++){
            int t = i*256 + tid;                 // float4 idx 0..1023
            int m = t>>2, q = t&3;
            float4 v = ldg4(lpTn + t*4);
            *(float4*)&lp_s[(m>>1)*LPP + (m&1)*16 + q*4] = v;
        }
    }
    #pragma unroll
    for (int f0=0; f0<2; f0++){
        int f = f0*256 + tid;                 // float4 index 0..319
        if (f < 320){
            int row = f>>2, q = f&3;
            int cl = row/20, k = row - cl*20;
            *(float4*)&wt_s[row*16 + q*4] = ldg4(wgt + k*512 + (c0+cl)*16 + q*4);
        }
    }
    if (FIRST){
        for (int t = tid; t < NK*16; t += 256) g_s[t] = g_in[n*320 + t];
    } else {
        if (tid < 90){   // 90 float4 = 360 floats -> red_s (tmp)
            float4 acc = make_float4(0.f,0.f,0.f,0.f);
            const float* p = Pprev + (size_t)n*NSPLIT*NK*PROW + tid*4;
            #pragma unroll
            for (int s=0;s<NSPLIT;s++){
                float4 v = ldg4(p + s*NK*PROW);
                acc.x += v.x; acc.y += v.y; acc.z += v.z; acc.w += v.w;
            }
            *(float4*)&red_s[tid*4] = acc;
        }
    }
    __syncthreads();

    // ---- A2 (FIRST): write lpT rows for later kernels ----
    if (FIRST){
        #pragma unroll
        for (int i=0;i<4;i++){
            int t = i*256 + tid;                 // float4 idx 0..1023
            int m = t>>2, q = t&3;
            float4 v = *(const float4*)&lp_s[(m>>1)*LPP + (m&1)*16 + q*4];
            *(float4*)(lpTn + t*4) = v;
        }
    }

    // ---- B: g from tmp (non-FIRST) ----
    if (!FIRST){
        for (int t = tid; t < NK*16; t += 256){
            int k = t>>4, d = t&15;
            g_s[t] = red_s[k*PROW + d] / red_s[k*PROW + 16];
        }
        __syncthreads();
    }

    // ---- C: build fused rows (80 rows) ----
    if (tid < CPB*NK){
        int cl = tid/20, k = tid - cl*20;
        float w[16], g[16];
        #pragma unroll
        for (int q=0;q<4;q++){
            float4 wv = *(const float4*)&wt_s[(cl*20+k)*16 + q*4];
            w[q*4+0]=wv.x; w[q*4+1]=wv.y; w[q*4+2]=wv.z; w[q*4+3]=wv.w;
            float4 gv = *(const float4*)&g_s[k*16 + q*4];
            g[q*4+0]=gv.x; g[q*4+1]=gv.y; g[q*4+2]=gv.z; g[q*4+3]=gv.w;
        }
        float* row = &mw_s[(cl*20 + k)*ROWF];
        #pragma unroll
        for (int i=0;i<4;i++)
            #pragma unroll
            for (int j=0;j<4;j++){
                float a = w[j*4+0]*g[i*4+0] + w[j*4+1]*g[i*4+1]
                        + w[j*4+2]*g[i*4+2] + w[j*4+3]*g[i*4+3];
                row[i*4+j] = -2.f*a;
            }
        int p = 0;
        #pragma unroll
        for (int j=0;j<4;j++)
            #pragma unroll
            for (int jp=j;jp<4;jp++){
                float a = w[j*4+0]*w[jp*4+0] + w[j*4+1]*w[jp*4+1]
                        + w[j*4+2]*w[jp*4+2] + w[j*4+3]*w[jp*4+3];
                row[16+p] = (j==jp)? a : 2.f*a;
                p++;
            }
        float cst = 0.f;
        #pragma unroll
        for (int x=0;x<16;x++) cst += g[x]*g[x];
        row[26] = cst;
        row[27] = 0.f;
    }
    __syncthreads();

    // ---- phase 1: thread=(m-pair, kh); rows reused for both m ----
    {
        const int mp = tid >> 1, kh = tid & 1;
        const float* lpr = &lp_s[mp*LPP];
        float lp0[16], lp1[16];
        #pragma unroll
        for (int q=0;q<4;q++){
            float4 v0 = *(const float4*)&lpr[q*4];
            lp0[q*4+0]=v0.x; lp0[q*4+1]=v0.y; lp0[q*4+2]=v0.z; lp0[q*4+3]=v0.w;
            float4 v1 = *(const float4*)&lpr[16 + q*4];
            lp1[q*4+0]=v1.x; lp1[q*4+1]=v1.y; lp1[q*4+2]=v1.z; lp1[q*4+3]=v1.w;
        }
        float QS0[10], QS1[10];
        {
            int p=0;
            #pragma unroll
            for (int j=0;j<4;j++)
                #pragma unroll
                for (int jp=j;jp<4;jp++){
                    QS0[p] = lp0[j]*lp0[jp] + lp0[4+j]*lp0[4+jp]
                           + lp0[8+j]*lp0[8+jp] + lp0[12+j]*lp0[12+jp];
                    QS1[p] = lp1[j]*lp1[jp] + lp1[4+j]*lp1[4+jp]
                           + lp1[8+j]*lp1[8+jp] + lp1[12+j]*lp1[12+jp];
                    p++;
                }
        }
        const int cl = tid >> 6;   // wave id == cl
        const float* mwb = &mw_s[(cl*20 + kh*10)*ROWF];
        float invs0[10], invs1[10], qvs0[10], qvs1[10];
        float rd0 = 0.f, rd1 = 0.f;
        #pragma unroll
        for (int i=0;i<10;i++){
            const float* row = mwb + i*ROWF;
            float4 w0 = *(const float4*)(row+0);
            float4 w1 = *(const float4*)(row+4);
            float4 w2 = *(const float4*)(row+8);
            float4 w3 = *(const float4*)(row+12);
            float4 a0 = *(const float4*)(row+16);
            float4 a1 = *(const float4*)(row+20);
            float4 a2 = *(const float4*)(row+24);   // mq8, mq9, cst, pad
            float qv0 = a0.x*QS0[0] + a0.y*QS0[1] + a0.z*QS0[2] + a0.w*QS0[3]
                      + a1.x*QS0[4] + a1.y*QS0[5] + a1.z*QS0[6] + a1.w*QS0[7]
                      + a2.x*QS0[8] + a2.y*QS0[9];
            float qv1 = a0.x*QS1[0] + a0.y*QS1[1] + a0.z*QS1[2] + a0.w*QS1[3]
                      + a1.x*QS1[4] + a1.y*QS1[5] + a1.z*QS1[6] + a1.w*QS1[7]
                      + a2.x*QS1[8] + a2.y*QS1[9];
            float rn0 = a2.z + qv0
                + w0.x*lp0[0] + w0.y*lp0[1] + w0.z*lp0[2] + w0.w*lp0[3]
                + w1.x*lp0[4] + w1.y*lp0[5] + w1.z*lp0[6] + w1.w*lp0[7]
                + w2.x*lp0[8] + w2.y*lp0[9] + w2.z*lp0[10]+ w2.w*lp0[11]
                + w3.x*lp0[12]+ w3.y*lp0[13]+ w3.z*lp0[14]+ w3.w*lp0[15];
            float rn1 = a2.z + qv1
                + w0.x*lp1[0] + w0.y*lp1[1] + w0.z*lp1[2] + w0.w*lp1[3]
                + w1.x*lp1[4] + w1.y*lp1[5] + w1.z*lp1[6] + w1.w*lp1[7]
                + w2.x*lp1[8] + w2.y*lp1[9] + w2.z*lp1[10]+ w2.w*lp1[11]
                + w3.x*lp1[12]+ w3.y*lp1[13]+ w3.z*lp1[14]+ w3.w*lp1[15];
            float i0 = frcp(rn0), i1 = frcp(rn1);
            invs0[i] = i0; invs1[i] = i1;
            if (MODE){ qvs0[i] = qv0; qvs1[i] = qv1; }
            rd0 += i0; rd1 += i1;
        }
        rd0 += __shfl_xor(rd0, 1, 64);
        rd1 += __shfl_xor(rd1, 1, 64);
        float ird0 = frcp(rd0), ird1 = frcp(rd1);
        #pragma unroll
        for (int i=0;i<10;i++){
            float t0 = invs0[i]*ird0, t1 = invs1[i]*ird1;
            float r0 = t0*t0, r1 = t1*t1;
            *(float2*)&r_s[(kh*10+i)*RST + mp*2] = make_float2(r0, r1);
            if (MODE){
                float rqp = r0*qvs0[i] + r1*qvs1[i];
                rqp += __shfl_xor(rqp, 2, 64);
                rqp += __shfl_xor(rqp, 4, 64);
                rqp += __shfl_xor(rqp, 8, 64);
                rqp += __shfl_xor(rqp, 16, 64);
                rqp += __shfl_xor(rqp, 32, 64);
                if ((tid & 62) == 0)              // lanes 0,1 of the wave
                    rqw_s[cl*24 + kh*10 + i] = rqp;
            }
        }
    }
    __syncthreads();

    // ---- phase 3: T[w,k,ij] = sum over this wave's 64 m of r*lp ----
    const int k3 = tid & 31, mi = tid >> 5;      // mi 0..7, 32 m each
    const int kk = (k3 < NK)? k3 : k3 - NK;
    const int mbase = mi*32;
    float T[16]; float sacc = 0.f;
    #pragma unroll
    for (int d=0;d<16;d++) T[d]=0.f;

    auto acc_m = [&](float r, int m){
        float4 v0, v1, v2, v3;
        if (FIRST){
            const float* lr = &lp_s[(m>>1)*LPP + (m&1)*16];
            v0 = *(const float4*)&lr[0];
            v1 = *(const float4*)&lr[4];
            v2 = *(const float4*)&lr[8];
            v3 = *(const float4*)&lr[12];
        } else {
            const float* lr = lpTn + m*16;       // global, L1-broadcast
            v0 = ldg4(lr+0);
            v1 = ldg4(lr+4);
            v2 = ldg4(lr+8);
            v3 = ldg4(lr+12);
        }
        T[0]+=r*v0.x; T[1]+=r*v0.y; T[2]+=r*v0.z; T[3]+=r*v0.w;
        T[4]+=r*v1.x; T[5]+=r*v1.y; T[6]+=r*v1.z; T[7]+=r*v1.w;
        T[8]+=r*v2.x; T[9]+=r*v2.y; T[10]+=r*v2.z; T[11]+=r*v2.w;
        T[12]+=r*v3.x; T[13]+=r*v3.y; T[14]+=r*v3.z; T[15]+=r*v3.w;
        sacc += r;
    };
    #pragma unroll
    for (int j4=0;j4<8;j4++){
        float4 rv = *(const float4*)&r_s[kk*RST + mbase + j4*4];
        acc_m(rv.x, mbase + j4*4 + 0);
        acc_m(rv.y, mbase + j4*4 + 1);
        acc_m(rv.z, mbase + j4*4 + 2);
        acc_m(rv.w, mbase + j4*4 + 3);
    }
    #pragma unroll
    for (int d=0;d<16;d++) T[d] += __shfl_xor(T[d], 32, 64);
    sacc += __shfl_xor(sacc, 32, 64);
    if ((k3 < NK) && !(tid & 32)){
        float* row = &red_s[((tid>>6)*NK + k3)*PROW];
        *(float4*)(row+0)  = make_float4(T[0],T[1],T[2],T[3]);
        *(float4*)(row+4)  = make_float4(T[4],T[5],T[6],T[7]);
        *(float4*)(row+8)  = make_float4(T[8],T[9],T[10],T[11]);
        *(float4*)(row+12) = make_float4(T[12],T[13],T[14],T[15]);
        row[16] = sacc;
    }
    __syncthreads();

    // ---- u-contract + P write (wave w == cl) ----
    for (int t = tid; t < NK*PROW; t += 256){
        int k = t/PROW, x = t - k*PROW;
        float acc = 0.f;
        if (x == 17){
            if (MODE)
                acc = rqw_s[0*24+k] + rqw_s[1*24+k] + rqw_s[2*24+k] + rqw_s[3*24+k];
        } else if (x == 16){
            #pragma unroll
            for (int w=0;w<4;w++) acc += red_s[(w*NK+k)*PROW + 16];
        } else {
            int i = x>>2, o = x&3;
            #pragma unroll
            for (int w=0;w<4;w++){
                float4 rv = *(const float4*)&red_s[(w*NK+k)*PROW + i*4];
                acc += rv.x*wt_s[(w*20+k)*16 + 0*4 + o]
                     + rv.y*wt_s[(w*20+k)*16 + 1*4 + o]
                     + rv.z*wt_s[(w*20+k)*16 + 2*4 + o]
                     + rv.w*wt_s[(w*20+k)*16 + 3*4 + o];
            }
        }
        Pout[(size_t)(n*NSPLIT+split)*NK*PROW + t] = acc;
    }
}

extern "C" void kernel_launch(void* const* d_in, const int* in_sizes, int n_in,
                              void* d_out, int out_size, void* d_ws, size_t ws_size,
                              hipStream_t stream)
{
    const float* l    = (const float*)d_in[0];
    const float* g    = (const float*)d_in[1];
    const float* wgt  = (const float*)d_in[2];
    const float* beta = (const float*)d_in[3];
    float* out = (float*)d_out;
    float* ws  = (float*)d_ws;

    const size_t PSZ = (size_t)NB * NSPLIT * NK * PROW;   // 184320
    float* PA  = ws;
    float* PB  = PA + PSZ;
    float* lpT = PB + PSZ;                                // 64*2048*16 = 2.1M floats

    dim3 gridR(NSPLIT, NB), gridS(4, NB), blk(256);
    k_route<1,0><<<gridR, blk, 0, stream>>>(l, wgt, g, nullptr, PA, lpT);  // r1 (g0)
    k_route<0,0><<<gridR, blk, 0, stream>>>(l, wgt, nullptr, PA, PB, lpT); // r2 (g1)
    k_route<0,1><<<gridR, blk, 0, stream>>>(l, wgt, nullptr, PB, PA, lpT); // r3 (g2) + rqv
    k_redfinal<<<gridS, blk, 0, stream>>>(PA, beta, out);                  // g3, sigma, a
}

// Round 15
// 43.539 us; speedup vs baseline: 1.1439x; 1.1439x over previous
//
#include <hip/hip_runtime.h>
#include <math.h>

// Fuzzy capsule routing, MI355X — round 14 (resubmit after infra failure):
// R11 base (lpT reverted) + phase-3 k-pair amortization: thread =
// (k-pair, 16 m), each lp b128 feeds TWO k accumulators -> phase-3 DS
// issues 136 -> 72 per wave.

#define NB 64
#define NK 20
#define NSPLIT 8
#define CPB 4
#define LPP 36            // lp pair-row stride: [mp][ m&1 ? 16..31 : 0..15 ]
#define RST 260           // r_s row stride
#define ROWF 28           // fused row: [0..15]=-2Wg, [16..25]=WW^T, [26]=|g|^2
#define PROW 18           // P row per k: [0..15]=u, [16]=s, [17]=rqv

__device__ __forceinline__ float frcp(float x){ return __builtin_amdgcn_rcpf(x); }
__device__ __forceinline__ float4 ldg4(const float* p){ return *(const float4*)p; }

// ---------------- final reduce: g3, sigma, a ----------------
__global__ __launch_bounds__(256)
void k_redfinal(const float* __restrict__ P, const float* __restrict__ beta,
                float* __restrict__ out)
{
    const int q = blockIdx.x, n = blockIdx.y, tid = threadIdx.x;
    __shared__ float tmp_s[5*PROW];
    if (tid < 5*PROW){
        float acc = 0.f;
        const float* p = P + (size_t)n*NSPLIT*NK*PROW + q*5*PROW + tid;
        #pragma unroll
        for (int s=0;s<NSPLIT;s++) acc += p[s*NK*PROW];
        tmp_s[tid] = acc;
    }
    __syncthreads();
    if (tid < 80){
        int kloc = tid>>4, d = tid&15;
        out[1280 + n*320 + q*80 + tid] = tmp_s[kloc*PROW + d] / tmp_s[kloc*PROW + 16];
    }
    if (tid < 5){
        const int k = q*5 + tid;
        float s   = tmp_s[tid*PROW + 16];
        float rqv = tmp_s[tid*PROW + 17];
        float usq = 0.f;
        #pragma unroll
        for (int d=0;d<16;d++){ float u = tmp_s[tid*PROW + d]; usq += u*u; }
        float is = 1.f/s;
        float sig = is*rqv - (is*is)*usq;     // (1/s)Sum r|V|^2 - |g3|^2
        float z = beta[k] - 0.5f*logf(sig);   // LAMBDA = 1
        out[n*NK + k] = 1.f/(1.f + expf(-z));
    }
}

// ---------------- routing iteration ----------------
// FIRST: g from g_in. Else: in-block reduce of Pprev (red_s as tmp) -> g.
// MODE1: also accumulate rqv (wave-reduced in phase 1).
template<int FIRST, int MODE>
__global__ __launch_bounds__(256, 2)
void k_route(const float* __restrict__ l, const float* __restrict__ wgt,
             const float* __restrict__ g_in, const float* __restrict__ Pprev,
             float* __restrict__ Pout)
{
    const int split = blockIdx.x, n = blockIdx.y, tid = threadIdx.x;
    const int c0 = split*CPB;

    __shared__ __align__(16) float lp_s[128*LPP];        // 4608
    __shared__ __align__(16) float r_s[NK*RST];          // 5200
    __shared__ __align__(16) float mw_s[CPB*NK*ROWF];    // 2240
    __shared__ __align__(16) float wt_s[CPB*NK*16];      // 1280
    __shared__ __align__(16) float red_s[4*NK*PROW];     // 1440 (tmp alias early)
    __shared__ __align__(16) float rqw_s[4*24];          // 96
    __shared__ __align__(16) float g_s[NK*16];           // 320

    // ---- A: stage lp (paired rows), W; g source ----
    const float* lsrc = l + ((size_t)n*32 + c0)*1024;
    #pragma unroll
    for (int i=0;i<16;i++){
        int t = i*256 + tid;
        int cl = t>>10, dd = (t>>6)&15, wh = t&63;
        int m = cl*64 + wh;
        lp_s[(m>>1)*LPP + (m&1)*16 + dd] = lsrc[t];
    }
    #pragma unroll
    for (int f0=0; f0<2; f0++){
        int f = f0*256 + tid;                 // float4 index 0..319
        if (f < 320){
            int row = f>>2, q = f&3;
            int cl = row/20, k = row - cl*20;
            *(float4*)&wt_s[row*16 + q*4] = ldg4(wgt + k*512 + (c0+cl)*16 + q*4);
        }
    }
    if (FIRST){
        for (int t = tid; t < NK*16; t += 256) g_s[t] = g_in[n*320 + t];
    } else {
        if (tid < 90){   // 90 float4 = 360 floats -> red_s (tmp)
            float4 acc = make_float4(0.f,0.f,0.f,0.f);
            const float* p = Pprev + (size_t)n*NSPLIT*NK*PROW + tid*4;
            #pragma unroll
            for (int s=0;s<NSPLIT;s++){
                float4 v = ldg4(p + s*NK*PROW);
                acc.x += v.x; acc.y += v.y; acc.z += v.z; acc.w += v.w;
            }
            *(float4*)&red_s[tid*4] = acc;
        }
    }
    __syncthreads();

    // ---- B: g from tmp (non-FIRST) ----
    if (!FIRST){
        for (int t = tid; t < NK*16; t += 256){
            int k = t>>4, d = t&15;
            g_s[t] = red_s[k*PROW + d] / red_s[k*PROW + 16];
        }
        __syncthreads();
    }

    // ---- C: build fused rows (80 rows) ----
    if (tid < CPB*NK){
        int cl = tid/20, k = tid - cl*20;
        float w[16], g[16];
        #pragma unroll
        for (int q=0;q<4;q++){
            float4 wv = *(const float4*)&wt_s[(cl*20+k)*16 + q*4];
            w[q*4+0]=wv.x; w[q*4+1]=wv.y; w[q*4+2]=wv.z; w[q*4+3]=wv.w;
            float4 gv = *(const float4*)&g_s[k*16 + q*4];
            g[q*4+0]=gv.x; g[q*4+1]=gv.y; g[q*4+2]=gv.z; g[q*4+3]=gv.w;
        }
        float* row = &mw_s[(cl*20 + k)*ROWF];
        #pragma unroll
        for (int i=0;i<4;i++)
            #pragma unroll
            for (int j=0;j<4;j++){
                float a = w[j*4+0]*g[i*4+0] + w[j*4+1]*g[i*4+1]
                        + w[j*4+2]*g[i*4+2] + w[j*4+3]*g[i*4+3];
                row[i*4+j] = -2.f*a;
            }
        int p = 0;
        #pragma unroll
        for (int j=0;j<4;j++)
            #pragma unroll
            for (int jp=j;jp<4;jp++){
                float a = w[j*4+0]*w[jp*4+0] + w[j*4+1]*w[jp*4+1]
                        + w[j*4+2]*w[jp*4+2] + w[j*4+3]*w[jp*4+3];
                row[16+p] = (j==jp)? a : 2.f*a;
                p++;
            }
        float cst = 0.f;
        #pragma unroll
        for (int x=0;x<16;x++) cst += g[x]*g[x];
        row[26] = cst;
        row[27] = 0.f;
    }
    __syncthreads();

    // ---- phase 1: thread=(m-pair, kh); rows reused for both m ----
    {
        const int mp = tid >> 1, kh = tid & 1;
        const float* lpr = &lp_s[mp*LPP];
        float lp0[16], lp1[16];
        #pragma unroll
        for (int q=0;q<4;q++){
            float4 v0 = *(const float4*)&lpr[q*4];
            lp0[q*4+0]=v0.x; lp0[q*4+1]=v0.y; lp0[q*4+2]=v0.z; lp0[q*4+3]=v0.w;
            float4 v1 = *(const float4*)&lpr[16 + q*4];
            lp1[q*4+0]=v1.x; lp1[q*4+1]=v1.y; lp1[q*4+2]=v1.z; lp1[q*4+3]=v1.w;
        }
        float QS0[10], QS1[10];
        {
            int p=0;
            #pragma unroll
            for (int j=0;j<4;j++)
                #pragma unroll
                for (int jp=j;jp<4;jp++){
                    QS0[p] = lp0[j]*lp0[jp] + lp0[4+j]*lp0[4+jp]
                           + lp0[8+j]*lp0[8+jp] + lp0[12+j]*lp0[12+jp];
                    QS1[p] = lp1[j]*lp1[jp] + lp1[4+j]*lp1[4+jp]
                           + lp1[8+j]*lp1[8+jp] + lp1[12+j]*lp1[12+jp];
                    p++;
                }
        }
        const int cl = tid >> 6;   // wave id == cl (wave covers 32 mp = 64 m)
        const float* mwb = &mw_s[(cl*20 + kh*10)*ROWF];
        float invs0[10], invs1[10], qvs0[10], qvs1[10];
        float rd0 = 0.f, rd1 = 0.f;
        #pragma unroll
        for (int i=0;i<10;i++){
            const float* row = mwb + i*ROWF;
            float4 w0 = *(const float4*)(row+0);
            float4 w1 = *(const float4*)(row+4);
            float4 w2 = *(const float4*)(row+8);
            float4 w3 = *(const float4*)(row+12);
            float4 a0 = *(const float4*)(row+16);
            float4 a1 = *(const float4*)(row+20);
            float4 a2 = *(const float4*)(row+24);   // mq8, mq9, cst, pad
            float qv0 = a0.x*QS0[0] + a0.y*QS0[1] + a0.z*QS0[2] + a0.w*QS0[3]
                      + a1.x*QS0[4] + a1.y*QS0[5] + a1.z*QS0[6] + a1.w*QS0[7]
                      + a2.x*QS0[8] + a2.y*QS0[9];
            float qv1 = a0.x*QS1[0] + a0.y*QS1[1] + a0.z*QS1[2] + a0.w*QS1[3]
                      + a1.x*QS1[4] + a1.y*QS1[5] + a1.z*QS1[6] + a1.w*QS1[7]
                      + a2.x*QS1[8] + a2.y*QS1[9];
            float rn0 = a2.z + qv0
                + w0.x*lp0[0] + w0.y*lp0[1] + w0.z*lp0[2] + w0.w*lp0[3]
                + w1.x*lp0[4] + w1.y*lp0[5] + w1.z*lp0[6] + w1.w*lp0[7]
                + w2.x*lp0[8] + w2.y*lp0[9] + w2.z*lp0[10]+ w2.w*lp0[11]
                + w3.x*lp0[12]+ w3.y*lp0[13]+ w3.z*lp0[14]+ w3.w*lp0[15];
            float rn1 = a2.z + qv1
                + w0.x*lp1[0] + w0.y*lp1[1] + w0.z*lp1[2] + w0.w*lp1[3]
                + w1.x*lp1[4] + w1.y*lp1[5] + w1.z*lp1[6] + w1.w*lp1[7]
                + w2.x*lp1[8] + w2.y*lp1[9] + w2.z*lp1[10]+ w2.w*lp1[11]
                + w3.x*lp1[12]+ w3.y*lp1[13]+ w3.z*lp1[14]+ w3.w*lp1[15];
            float i0 = frcp(rn0), i1 = frcp(rn1);
            invs0[i] = i0; invs1[i] = i1;
            if (MODE){ qvs0[i] = qv0; qvs1[i] = qv1; }
            rd0 += i0; rd1 += i1;
        }
        rd0 += __shfl_xor(rd0, 1, 64);
        rd1 += __shfl_xor(rd1, 1, 64);
        float ird0 = frcp(rd0), ird1 = frcp(rd1);
        #pragma unroll
        for (int i=0;i<10;i++){
            float t0 = invs0[i]*ird0, t1 = invs1[i]*ird1;
            float r0 = t0*t0, r1 = t1*t1;
            *(float2*)&r_s[(kh*10+i)*RST + mp*2] = make_float2(r0, r1);
            if (MODE){
                float rqp = r0*qvs0[i] + r1*qvs1[i];
                rqp += __shfl_xor(rqp, 2, 64);
                rqp += __shfl_xor(rqp, 4, 64);
                rqp += __shfl_xor(rqp, 8, 64);
                rqp += __shfl_xor(rqp, 16, 64);
                rqp += __shfl_xor(rqp, 32, 64);
                if ((tid & 62) == 0)              // lanes 0,1 of the wave
                    rqw_s[cl*24 + kh*10 + i] = rqp;
            }
        }
    }
    __syncthreads();

    // ---- phase 3: thread=(k-pair, 16 m); lp load feeds TWO k accumulators ----
    {
        const int k2 = tid & 15;                 // 0..9 used, 10..15 alias
        const int mi = tid >> 4;                 // 0..15, 16 m each
        const int kkA = (k2 < 10)? 2*k2 : 2*(k2-10);
        const int kkB = kkA + 1;
        const int mbase = mi*16;
        float TA[16], TB[16]; float sA = 0.f, sB = 0.f;
        #pragma unroll
        for (int d=0;d<16;d++){ TA[d]=0.f; TB[d]=0.f; }

        auto acc_m = [&](float rA, float rB, int m){
            const float* lr = &lp_s[(m>>1)*LPP + (m&1)*16];
            float4 v0 = *(const float4*)&lr[0];
            float4 v1 = *(const float4*)&lr[4];
            float4 v2 = *(const float4*)&lr[8];
            float4 v3 = *(const float4*)&lr[12];
            TA[0]+=rA*v0.x; TA[1]+=rA*v0.y; TA[2]+=rA*v0.z; TA[3]+=rA*v0.w;
            TA[4]+=rA*v1.x; TA[5]+=rA*v1.y; TA[6]+=rA*v1.z; TA[7]+=rA*v1.w;
            TA[8]+=rA*v2.x; TA[9]+=rA*v2.y; TA[10]+=rA*v2.z; TA[11]+=rA*v2.w;
            TA[12]+=rA*v3.x; TA[13]+=rA*v3.y; TA[14]+=rA*v3.z; TA[15]+=rA*v3.w;
            TB[0]+=rB*v0.x; TB[1]+=rB*v0.y; TB[2]+=rB*v0.z; TB[3]+=rB*v0.w;
            TB[4]+=rB*v1.x; TB[5]+=rB*v1.y; TB[6]+=rB*v1.z; TB[7]+=rB*v1.w;
            TB[8]+=rB*v2.x; TB[9]+=rB*v2.y; TB[10]+=rB*v2.z; TB[11]+=rB*v2.w;
            TB[12]+=rB*v3.x; TB[13]+=rB*v3.y; TB[14]+=rB*v3.z; TB[15]+=rB*v3.w;
            sA += rA; sB += rB;
        };
        #pragma unroll
        for (int j4=0;j4<4;j4++){
            float4 rA = *(const float4*)&r_s[kkA*RST + mbase + j4*4];
            float4 rB = *(const float4*)&r_s[kkB*RST + mbase + j4*4];
            acc_m(rA.x, rB.x, mbase + j4*4 + 0);
            acc_m(rA.y, rB.y, mbase + j4*4 + 1);
            acc_m(rA.z, rB.z, mbase + j4*4 + 2);
            acc_m(rA.w, rB.w, mbase + j4*4 + 3);
        }
        // reduce across the wave's 4 mi groups (lanes tid^16, tid^32)
        #pragma unroll
        for (int d=0;d<16;d++){
            TA[d] += __shfl_xor(TA[d], 16, 64);
            TA[d] += __shfl_xor(TA[d], 32, 64);
            TB[d] += __shfl_xor(TB[d], 16, 64);
            TB[d] += __shfl_xor(TB[d], 32, 64);
        }
        sA += __shfl_xor(sA, 16, 64); sA += __shfl_xor(sA, 32, 64);
        sB += __shfl_xor(sB, 16, 64); sB += __shfl_xor(sB, 32, 64);
        if ((k2 < 10) && !(tid & 48)){           // one lane per (wave, k2)
            const int w = tid >> 6;              // wave covers m [w*64,(w+1)*64)
            float* rowA = &red_s[(w*NK + kkA)*PROW];
            *(float4*)(rowA+0)  = make_float4(TA[0],TA[1],TA[2],TA[3]);
            *(float4*)(rowA+4)  = make_float4(TA[4],TA[5],TA[6],TA[7]);
            *(float4*)(rowA+8)  = make_float4(TA[8],TA[9],TA[10],TA[11]);
            *(float4*)(rowA+12) = make_float4(TA[12],TA[13],TA[14],TA[15]);
            rowA[16] = sA;
            float* rowB = &red_s[(w*NK + kkB)*PROW];
            *(float4*)(rowB+0)  = make_float4(TB[0],TB[1],TB[2],TB[3]);
            *(float4*)(rowB+4)  = make_float4(TB[4],TB[5],TB[6],TB[7]);
            *(float4*)(rowB+8)  = make_float4(TB[8],TB[9],TB[10],TB[11]);
            *(float4*)(rowB+12) = make_float4(TB[12],TB[13],TB[14],TB[15]);
            rowB[16] = sB;
        }
    }
    __syncthreads();

    // ---- u-contract + P write (wave w == cl) ----
    for (int t = tid; t < NK*PROW; t += 256){
        int k = t/PROW, x = t - k*PROW;
        float acc = 0.f;
        if (x == 17){
            if (MODE)
                acc = rqw_s[0*24+k] + rqw_s[1*24+k] + rqw_s[2*24+k] + rqw_s[3*24+k];
        } else if (x == 16){
            #pragma unroll
            for (int w=0;w<4;w++) acc += red_s[(w*NK+k)*PROW + 16];
        } else {
            int i = x>>2, o = x&3;
            #pragma unroll
            for (int w=0;w<4;w++){
                float4 rv = *(const float4*)&red_s[(w*NK+k)*PROW + i*4];
                acc += rv.x*wt_s[(w*20+k)*16 + 0*4 + o]
                     + rv.y*wt_s[(w*20+k)*16 + 1*4 + o]
                     + rv.z*wt_s[(w*20+k)*16 + 2*4 + o]
                     + rv.w*wt_s[(w*20+k)*16 + 3*4 + o];
            }
        }
        Pout[(size_t)(n*NSPLIT+split)*NK*PROW + t] = acc;
    }
}

extern "C" void kernel_launch(void* const* d_in, const int* in_sizes, int n_in,
                              void* d_out, int out_size, void* d_ws, size_t ws_size,
                              hipStream_t stream)
{
    const float* l    = (const float*)d_in[0];
    const float* g    = (const float*)d_in[1];
    const float* wgt  = (const float*)d_in[2];
    const float* beta = (const float*)d_in[3];
    float* out = (float*)d_out;
    float* ws  = (float*)d_ws;

    const size_t PSZ = (size_t)NB * NSPLIT * NK * PROW;   // 184320
    float* PA = ws;
    float* PB = PA + PSZ;

    dim3 gridR(NSPLIT, NB), gridS(4, NB), blk(256);
    k_route<1,0><<<gridR, blk, 0, stream>>>(l, wgt, g, nullptr, PA);  // r1 (g0)
    k_route<0,0><<<gridR, blk, 0, stream>>>(l, wgt, nullptr, PA, PB); // r2 (g1)
    k_route<0,1><<<gridR, blk, 0, stream>>>(l, wgt, nullptr, PB, PA); // r3 (g2) + rqv
    k_redfinal<<<gridS, blk, 0, stream>>>(PA, beta, out);             // g3, sigma, a
}

// Round 18
// 41.008 us; speedup vs baseline: 1.2145x; 1.0617x over previous
//
#include <hip/hip_runtime.h>
#include <math.h>

// Fuzzy capsule routing, MI355X — round 16 (2nd resubmit after infra failures):
// R11 (best, 42.0us) + staging trim: thread owns m=tid, 16 dd-strided
// coalesced global b32 loads -> 4 b128 LDS writes (was 16 b32 DS writes).
// Phase 3 in R11 form (k-pair reverted: __shfl is ds_bpermute, a DS-pipe op).

#define NB 64
#define NK 20
#define NSPLIT 8
#define CPB 4
#define LPP 36            // lp pair-row stride: [mp][ m&1 ? 16..31 : 0..15 ]
#define RST 260           // r_s row stride
#define ROWF 28           // fused row: [0..15]=-2Wg, [16..25]=WW^T, [26]=|g|^2
#define PROW 18           // P row per k: [0..15]=u, [16]=s, [17]=rqv

__device__ __forceinline__ float frcp(float x){ return __builtin_amdgcn_rcpf(x); }
__device__ __forceinline__ float4 ldg4(const float* p){ return *(const float4*)p; }

// ---------------- final reduce: g3, sigma, a ----------------
__global__ __launch_bounds__(256)
void k_redfinal(const float* __restrict__ P, const float* __restrict__ beta,
                float* __restrict__ out)
{
    const int q = blockIdx.x, n = blockIdx.y, tid = threadIdx.x;
    __shared__ float tmp_s[5*PROW];
    if (tid < 5*PROW){
        float acc = 0.f;
        const float* p = P + (size_t)n*NSPLIT*NK*PROW + q*5*PROW + tid;
        #pragma unroll
        for (int s=0;s<NSPLIT;s++) acc += p[s*NK*PROW];
        tmp_s[tid] = acc;
    }
    __syncthreads();
    if (tid < 80){
        int kloc = tid>>4, d = tid&15;
        out[1280 + n*320 + q*80 + tid] = tmp_s[kloc*PROW + d] / tmp_s[kloc*PROW + 16];
    }
    if (tid < 5){
        const int k = q*5 + tid;
        float s   = tmp_s[tid*PROW + 16];
        float rqv = tmp_s[tid*PROW + 17];
        float usq = 0.f;
        #pragma unroll
        for (int d=0;d<16;d++){ float u = tmp_s[tid*PROW + d]; usq += u*u; }
        float is = 1.f/s;
        float sig = is*rqv - (is*is)*usq;     // (1/s)Sum r|V|^2 - |g3|^2
        float z = beta[k] - 0.5f*logf(sig);   // LAMBDA = 1
        out[n*NK + k] = 1.f/(1.f + expf(-z));
    }
}

// ---------------- routing iteration ----------------
// FIRST: g from g_in. Else: in-block reduce of Pprev (red_s as tmp) -> g.
// MODE1: also accumulate rqv (wave-reduced in phase 1).
template<int FIRST, int MODE>
__global__ __launch_bounds__(256, 2)
void k_route(const float* __restrict__ l, const float* __restrict__ wgt,
             const float* __restrict__ g_in, const float* __restrict__ Pprev,
             float* __restrict__ Pout)
{
    const int split = blockIdx.x, n = blockIdx.y, tid = threadIdx.x;
    const int c0 = split*CPB;

    __shared__ __align__(16) float lp_s[128*LPP];        // 4608
    __shared__ __align__(16) float r_s[NK*RST];          // 5200
    __shared__ __align__(16) float mw_s[CPB*NK*ROWF];    // 2240
    __shared__ __align__(16) float wt_s[CPB*NK*16];      // 1280
    __shared__ __align__(16) float red_s[4*NK*PROW];     // 1440 (tmp alias early)
    __shared__ __align__(16) float rqw_s[4*24];          // 96
    __shared__ __align__(16) float g_s[NK*16];           // 320

    // ---- A: stage lp (thread owns m=tid: 16 coalesced strided global b32
    //         -> 4 b128 DS writes), W; g source ----
    {
        const int m = tid, cl = m>>6, wh = m&63;
        const float* lsrcm = l + ((size_t)n*32 + c0 + cl)*1024 + wh;
        float v[16];
        #pragma unroll
        for (int dd=0; dd<16; dd++) v[dd] = lsrcm[dd*64];
        float* dst = &lp_s[(m>>1)*LPP + (m&1)*16];
        *(float4*)(dst+0)  = make_float4(v[0],v[1],v[2],v[3]);
        *(float4*)(dst+4)  = make_float4(v[4],v[5],v[6],v[7]);
        *(float4*)(dst+8)  = make_float4(v[8],v[9],v[10],v[11]);
        *(float4*)(dst+12) = make_float4(v[12],v[13],v[14],v[15]);
    }
    #pragma unroll
    for (int f0=0; f0<2; f0++){
        int f = f0*256 + tid;                 // float4 index 0..319
        if (f < 320){
            int row = f>>2, q = f&3;
            int cl = row/20, k = row - cl*20;
            *(float4*)&wt_s[row*16 + q*4] = ldg4(wgt + k*512 + (c0+cl)*16 + q*4);
        }
    }
    if (FIRST){
        for (int t = tid; t < NK*16; t += 256) g_s[t] = g_in[n*320 + t];
    } else {
        if (tid < 90){   // 90 float4 = 360 floats -> red_s (tmp)
            float4 acc = make_float4(0.f,0.f,0.f,0.f);
            const float* p = Pprev + (size_t)n*NSPLIT*NK*PROW + tid*4;
            #pragma unroll
            for (int s=0;s<NSPLIT;s++){
                float4 v = ldg4(p + s*NK*PROW);
                acc.x += v.x; acc.y += v.y; acc.z += v.z; acc.w += v.w;
            }
            *(float4*)&red_s[tid*4] = acc;
        }
    }
    __syncthreads();

    // ---- B: g from tmp (non-FIRST) ----
    if (!FIRST){
        for (int t = tid; t < NK*16; t += 256){
            int k = t>>4, d = t&15;
            g_s[t] = red_s[k*PROW + d] / red_s[k*PROW + 16];
        }
        __syncthreads();
    }

    // ---- C: build fused rows (80 rows) ----
    if (tid < CPB*NK){
        int cl = tid/20, k = tid - cl*20;
        float w[16], g[16];
        #pragma unroll
        for (int q=0;q<4;q++){
            float4 wv = *(const float4*)&wt_s[(cl*20+k)*16 + q*4];
            w[q*4+0]=wv.x; w[q*4+1]=wv.y; w[q*4+2]=wv.z; w[q*4+3]=wv.w;
            float4 gv = *(const float4*)&g_s[k*16 + q*4];
            g[q*4+0]=gv.x; g[q*4+1]=gv.y; g[q*4+2]=gv.z; g[q*4+3]=gv.w;
        }
        float* row = &mw_s[(cl*20 + k)*ROWF];
        #pragma unroll
        for (int i=0;i<4;i++)
            #pragma unroll
            for (int j=0;j<4;j++){
                float a = w[j*4+0]*g[i*4+0] + w[j*4+1]*g[i*4+1]
                        + w[j*4+2]*g[i*4+2] + w[j*4+3]*g[i*4+3];
                row[i*4+j] = -2.f*a;
            }
        int p = 0;
        #pragma unroll
        for (int j=0;j<4;j++)
            #pragma unroll
            for (int jp=j;jp<4;jp++){
                float a = w[j*4+0]*w[jp*4+0] + w[j*4+1]*w[jp*4+1]
                        + w[j*4+2]*w[jp*4+2] + w[j*4+3]*w[jp*4+3];
                row[16+p] = (j==jp)? a : 2.f*a;
                p++;
            }
        float cst = 0.f;
        #pragma unroll
        for (int x=0;x<16;x++) cst += g[x]*g[x];
        row[26] = cst;
        row[27] = 0.f;
    }
    __syncthreads();

    // ---- phase 1: thread=(m-pair, kh); rows reused for both m ----
    {
        const int mp = tid >> 1, kh = tid & 1;
        const float* lpr = &lp_s[mp*LPP];
        float lp0[16], lp1[16];
        #pragma unroll
        for (int q=0;q<4;q++){
            float4 v0 = *(const float4*)&lpr[q*4];
            lp0[q*4+0]=v0.x; lp0[q*4+1]=v0.y; lp0[q*4+2]=v0.z; lp0[q*4+3]=v0.w;
            float4 v1 = *(const float4*)&lpr[16 + q*4];
            lp1[q*4+0]=v1.x; lp1[q*4+1]=v1.y; lp1[q*4+2]=v1.z; lp1[q*4+3]=v1.w;
        }
        float QS0[10], QS1[10];
        {
            int p=0;
            #pragma unroll
            for (int j=0;j<4;j++)
                #pragma unroll
                for (int jp=j;jp<4;jp++){
                    QS0[p] = lp0[j]*lp0[jp] + lp0[4+j]*lp0[4+jp]
                           + lp0[8+j]*lp0[8+jp] + lp0[12+j]*lp0[12+jp];
                    QS1[p] = lp1[j]*lp1[jp] + lp1[4+j]*lp1[4+jp]
                           + lp1[8+j]*lp1[8+jp] + lp1[12+j]*lp1[12+jp];
                    p++;
                }
        }
        const int cl = tid >> 6;   // wave id == cl (wave covers 32 mp = 64 m)
        const float* mwb = &mw_s[(cl*20 + kh*10)*ROWF];
        float invs0[10], invs1[10], qvs0[10], qvs1[10];
        float rd0 = 0.f, rd1 = 0.f;
        #pragma unroll
        for (int i=0;i<10;i++){
            const float* row = mwb + i*ROWF;
            float4 w0 = *(const float4*)(row+0);
            float4 w1 = *(const float4*)(row+4);
            float4 w2 = *(const float4*)(row+8);
            float4 w3 = *(const float4*)(row+12);
            float4 a0 = *(const float4*)(row+16);
            float4 a1 = *(const float4*)(row+20);
            float4 a2 = *(const float4*)(row+24);   // mq8, mq9, cst, pad
            float qv0 = a0.x*QS0[0] + a0.y*QS0[1] + a0.z*QS0[2] + a0.w*QS0[3]
                      + a1.x*QS0[4] + a1.y*QS0[5] + a1.z*QS0[6] + a1.w*QS0[7]
                      + a2.x*QS0[8] + a2.y*QS0[9];
            float qv1 = a0.x*QS1[0] + a0.y*QS1[1] + a0.z*QS1[2] + a0.w*QS1[3]
                      + a1.x*QS1[4] + a1.y*QS1[5] + a1.z*QS1[6] + a1.w*QS1[7]
                      + a2.x*QS1[8] + a2.y*QS1[9];
            float rn0 = a2.z + qv0
                + w0.x*lp0[0] + w0.y*lp0[1] + w0.z*lp0[2] + w0.w*lp0[3]
                + w1.x*lp0[4] + w1.y*lp0[5] + w1.z*lp0[6] + w1.w*lp0[7]
                + w2.x*lp0[8] + w2.y*lp0[9] + w2.z*lp0[10]+ w2.w*lp0[11]
                + w3.x*lp0[12]+ w3.y*lp0[13]+ w3.z*lp0[14]+ w3.w*lp0[15];
            float rn1 = a2.z + qv1
                + w0.x*lp1[0] + w0.y*lp1[1] + w0.z*lp1[2] + w0.w*lp1[3]
                + w1.x*lp1[4] + w1.y*lp1[5] + w1.z*lp1[6] + w1.w*lp1[7]
                + w2.x*lp1[8] + w2.y*lp1[9] + w2.z*lp1[10]+ w2.w*lp1[11]
                + w3.x*lp1[12]+ w3.y*lp1[13]+ w3.z*lp1[14]+ w3.w*lp1[15];
            float i0 = frcp(rn0), i1 = frcp(rn1);
            invs0[i] = i0; invs1[i] = i1;
            if (MODE){ qvs0[i] = qv0; qvs1[i] = qv1; }
            rd0 += i0; rd1 += i1;
        }
        rd0 += __shfl_xor(rd0, 1, 64);
        rd1 += __shfl_xor(rd1, 1, 64);
        float ird0 = frcp(rd0), ird1 = frcp(rd1);
        #pragma unroll
        for (int i=0;i<10;i++){
            float t0 = invs0[i]*ird0, t1 = invs1[i]*ird1;
            float r0 = t0*t0, r1 = t1*t1;
            *(float2*)&r_s[(kh*10+i)*RST + mp*2] = make_float2(r0, r1);
            if (MODE){
                float rqp = r0*qvs0[i] + r1*qvs1[i];
                rqp += __shfl_xor(rqp, 2, 64);
                rqp += __shfl_xor(rqp, 4, 64);
                rqp += __shfl_xor(rqp, 8, 64);
                rqp += __shfl_xor(rqp, 16, 64);
                rqp += __shfl_xor(rqp, 32, 64);
                if ((tid & 62) == 0)              // lanes 0,1 of the wave
                    rqw_s[cl*24 + kh*10 + i] = rqp;
            }
        }
    }
    __syncthreads();

    // ---- phase 3: T[w,k,ij] = sum over this wave's 64 m of r*lp ----
    const int k3 = tid & 31, mi = tid >> 5;      // mi 0..7, 32 m each
    const int kk = (k3 < NK)? k3 : k3 - NK;
    const int mbase = mi*32;
    float T[16]; float sacc = 0.f;
    #pragma unroll
    for (int d=0;d<16;d++) T[d]=0.f;

    auto acc_m = [&](float r, int m){
        const float* lr = &lp_s[(m>>1)*LPP + (m&1)*16];
        float4 v0 = *(const float4*)&lr[0];
        float4 v1 = *(const float4*)&lr[4];
        float4 v2 = *(const float4*)&lr[8];
        float4 v3 = *(const float4*)&lr[12];
        T[0]+=r*v0.x; T[1]+=r*v0.y; T[2]+=r*v0.z; T[3]+=r*v0.w;
        T[4]+=r*v1.x; T[5]+=r*v1.y; T[6]+=r*v1.z; T[7]+=r*v1.w;
        T[8]+=r*v2.x; T[9]+=r*v2.y; T[10]+=r*v2.z; T[11]+=r*v2.w;
        T[12]+=r*v3.x; T[13]+=r*v3.y; T[14]+=r*v3.z; T[15]+=r*v3.w;
        sacc += r;
    };
    #pragma unroll
    for (int j4=0;j4<8;j4++){
        float4 rv = *(const float4*)&r_s[kk*RST + mbase + j4*4];
        acc_m(rv.x, mbase + j4*4 + 0);
        acc_m(rv.y, mbase + j4*4 + 1);
        acc_m(rv.z, mbase + j4*4 + 2);
        acc_m(rv.w, mbase + j4*4 + 3);
    }
    #pragma unroll
    for (int d=0;d<16;d++) T[d] += __shfl_xor(T[d], 32, 64);
    sacc += __shfl_xor(sacc, 32, 64);
    if ((k3 < NK) && !(tid & 32)){
        float* row = &red_s[((tid>>6)*NK + k3)*PROW];
        *(float4*)(row+0)  = make_float4(T[0],T[1],T[2],T[3]);
        *(float4*)(row+4)  = make_float4(T[4],T[5],T[6],T[7]);
        *(float4*)(row+8)  = make_float4(T[8],T[9],T[10],T[11]);
        *(float4*)(row+12) = make_float4(T[12],T[13],T[14],T[15]);
        row[16] = sacc;
    }
    __syncthreads();

    // ---- u-contract + P write (wave w == cl) ----
    for (int t = tid; t < NK*PROW; t += 256){
        int k = t/PROW, x = t - k*PROW;
        float acc = 0.f;
        if (x == 17){
            if (MODE)
                acc = rqw_s[0*24+k] + rqw_s[1*24+k] + rqw_s[2*24+k] + rqw_s[3*24+k];
        } else if (x == 16){
            #pragma unroll
            for (int w=0;w<4;w++) acc += red_s[(w*NK+k)*PROW + 16];
        } else {
            int i = x>>2, o = x&3;
            #pragma unroll
            for (int w=0;w<4;w++){
                float4 rv = *(const float4*)&red_s[(w*NK+k)*PROW + i*4];
                acc += rv.x*wt_s[(w*20+k)*16 + 0*4 + o]
                     + rv.y*wt_s[(w*20+k)*16 + 1*4 + o]
                     + rv.z*wt_s[(w*20+k)*16 + 2*4 + o]
                     + rv.w*wt_s[(w*20+k)*16 + 3*4 + o];
            }
        }
        Pout[(size_t)(n*NSPLIT+split)*NK*PROW + t] = acc;
    }
}

extern "C" void kernel_launch(void* const* d_in, const int* in_sizes, int n_in,
                              void* d_out, int out_size, void* d_ws, size_t ws_size,
                              hipStream_t stream)
{
    const float* l    = (const float*)d_in[0];
    const float* g    = (const float*)d_in[1];
    const float* wgt  = (const float*)d_in[2];
    const float* beta = (const float*)d_in[3];
    float* out = (float*)d_out;
    float* ws  = (float*)d_ws;

    const size_t PSZ = (size_t)NB * NSPLIT * NK * PROW;   // 184320
    float* PA = ws;
    float* PB = PA + PSZ;

    dim3 gridR(NSPLIT, NB), gridS(4, NB), blk(256);
    k_route<1,0><<<gridR, blk, 0, stream>>>(l, wgt, g, nullptr, PA);  // r1 (g0)
    k_route<0,0><<<gridR, blk, 0, stream>>>(l, wgt, nullptr, PA, PB); // r2 (g1)
    k_route<0,1><<<gridR, blk, 0, stream>>>(l, wgt, nullptr, PB, PA); // r3 (g2) + rqv
    k_redfinal<<<gridS, blk, 0, stream>>>(PA, beta, out);             // g3, sigma, a
}